// Round 3
// baseline (585.013 us; speedup 1.0000x reference)
//
#include <hip/hip_runtime.h>
#include <hip/hip_bf16.h>
#include <stdint.h>

// BidirectionalAttention2: two flash-attention passes over sim = v1 @ v2^T.
//  dir A: out1[l] = softmax_m(v2_mask ? -1e-7 : sim[l,m]) @ v2, rows zeroed by v1_mask
//  dir B: out2[m] = softmax_l(v1_mask ? -1e-7 : sim[l,m]) @ v1, rows zeroed by v2_mask
// Swapped-QK^T (S^T = mfma(K,Q)) + in-register online softmax, hi/lo bf16 split
// for the sim GEMM (3 mfma passes), query compaction (masked rows zeroed by
// zero_rows kernel, not memset).
// R3: (1) both dirs fused into ONE flash launch (2048 blocks);
//     (2) XCD-aware mapping: stream = blockIdx%8 -> batch%8, so all 16 q-tiles
//         of a (batch,dir) run on one XCD -> K/V L2 reuse (was 8x HBM refetch);
//     (3) __launch_bounds__(256,3) for 3 blocks/CU (LDS 48KB);
//     (4) prep fused into one launch; memset replaced by masked-row zeroing.

#define MASK_FILL -1e-07f

typedef unsigned short u16;
typedef __attribute__((ext_vector_type(8))) short short8;
typedef __attribute__((ext_vector_type(4))) float f32x4;
typedef __attribute__((ext_vector_type(4))) int int4v;
typedef __attribute__((ext_vector_type(4))) u16 u16x4;

#define NB 64
#define LL 1024
#define DD 256
#define BQ 64
#define BK 32
#define NKT (LL / BK)
#define ELEMS ((size_t)NB * LL * DD)

__device__ __forceinline__ unsigned bf16_rne(float f) {
    unsigned u = __float_as_uint(f);
    return (u + 0x7fffu + ((u >> 16) & 1u)) >> 16;
}

// ---- mask dtype detection + normalization ----------------------------------
// int32 0/1 masks: every word is 0 or 1 (no bits above bit0). Packed 1-byte
// bools: byte-packed words set higher bits w.p. ~1 over 4K random words.
// Scan 16KB (in-bounds under both interpretations).
__global__ __launch_bounds__(256) void mask_detect(
    const unsigned* __restrict__ m1, const unsigned* __restrict__ m2,
    int* __restrict__ flag)
{
    unsigned acc = 0;
    for (int i = threadIdx.x; i < 4096; i += 256)
        acc |= (m1[i] | m2[i]) & ~1u;
    __shared__ unsigned red[256];
    red[threadIdx.x] = acc;
    __syncthreads();
    for (int o = 128; o; o >>= 1) {
        if (threadIdx.x < o) red[threadIdx.x] |= red[threadIdx.x + o];
        __syncthreads();
    }
    if (threadIdx.x == 0) *flag = red[0] ? 1 : 0;
}

__global__ __launch_bounds__(256) void mask_convert(
    const void* __restrict__ m, const int* __restrict__ flag,
    int* __restrict__ outm)
{
    int i = blockIdx.x * 256 + threadIdx.x;
    int v;
    if (*flag) v = ((const unsigned char*)m)[i];   // 1-byte bool path
    else       v = ((const int*)m)[i];             // int32 path
    outm[i] = v ? 1 : 0;
}

// ---- zero only the masked output rows (flash writes all unmasked rows) ------
__global__ __launch_bounds__(256) void zero_rows(
    const int* __restrict__ cm1, const int* __restrict__ cm2,
    float* __restrict__ out)
{
    int r = blockIdx.x * 8 + (threadIdx.x >> 5);
    int c = (threadIdx.x & 31) * 8;
    int m = (r < NB * LL) ? cm1[r] : cm2[r - NB * LL];
    if (m) {
        f32x4 z4 = {0.f, 0.f, 0.f, 0.f};
        *(f32x4*)(out + (size_t)r * DD + c) = z4;
        *(f32x4*)(out + (size_t)r * DD + c + 4) = z4;
    }
}

// ---- pre-pass: fp32 -> (hi, lo) bf16 split + bf16 transpose, both tensors ---
// grid: 2*NB*64 blocks (tensor, b, ltile(16), dtile(4)), 256 threads.
__global__ __launch_bounds__(256) void prep2_kernel(
    const float* __restrict__ x1, u16* __restrict__ h1, u16* __restrict__ l1,
    u16* __restrict__ t1,
    const float* __restrict__ x2, u16* __restrict__ h2, u16* __restrict__ l2,
    u16* __restrict__ t2)
{
    __shared__ u16 t[64][65];
    int blk = blockIdx.x;
    int tensor = blk >> 12;
    blk &= 4095;
    const float* x = tensor ? x2 : x1;
    u16* h  = tensor ? h2 : h1;
    u16* lo = tensor ? l2 : l1;
    u16* xt = tensor ? t2 : t1;
    int b = blk >> 6, lt = (blk >> 2) & 15, dt = blk & 3;
    int l0 = lt * 64, d0 = dt * 64;
    int tid = threadIdx.x;
    int sub = tid >> 4;        // 0..15
    int c16 = tid & 15;        // 0..15 (float4 column)
#pragma unroll
    for (int p = 0; p < 4; ++p) {
        int row = p * 16 + sub;
        size_t gi = ((size_t)b * LL + l0 + row) * DD + d0 + c16 * 4;
        f32x4 v = *(const f32x4*)(x + gi);
        u16x4 hv, lv;
#pragma unroll
        for (int e = 0; e < 4; ++e) {
            unsigned hb = bf16_rne(v[e]);
            float hf = __uint_as_float(hb << 16);
            unsigned lb = bf16_rne(v[e] - hf);
            hv[e] = (u16)hb;
            lv[e] = (u16)lb;
            t[c16 * 4 + e][row] = (u16)hb;
        }
        *(u16x4*)(h + gi) = hv;
        *(u16x4*)(lo + gi) = lv;
    }
    __syncthreads();
#pragma unroll
    for (int p = 0; p < 4; ++p) {
        int d = p * 16 + sub;
        u16x4 ov;
#pragma unroll
        for (int e = 0; e < 4; ++e) ov[e] = t[d][c16 * 4 + e];
        *(u16x4*)(xt + ((size_t)b * DD + d0 + d) * LL + l0 + c16 * 4) = ov;
    }
}

// ---- pre-pass: per-batch compaction of unmasked rows ------------------------
__global__ __launch_bounds__(256) void build_qidx(
    const int* __restrict__ mask, int* __restrict__ qidx, int* __restrict__ qcnt)
{
    int b = blockIdx.x, tid = threadIdx.x;
    __shared__ int ps[256];
    const int* mb = mask + b * LL;
    int f[4], s = 0;
#pragma unroll
    for (int j = 0; j < 4; ++j) { f[j] = (mb[tid * 4 + j] == 0) ? 1 : 0; s += f[j]; }
    ps[tid] = s;
    __syncthreads();
    for (int off = 1; off < 256; off <<= 1) {
        int v = (tid >= off) ? ps[tid - off] : 0;
        __syncthreads();
        ps[tid] += v;
        __syncthreads();
    }
    int pos = (tid > 0) ? ps[tid - 1] : 0;
#pragma unroll
    for (int j = 0; j < 4; ++j)
        if (f[j]) qidx[b * LL + (pos++)] = tid * 4 + j;
    if (tid == 255) qcnt[b] = ps[255];
}

// ---- fused bidirectional flash attention, swapped-operand layout ------------
// grid 2048: i%8 = XCD stream -> b%8; within stream: qt fastest, then dir,
// then b-octet. 4 waves/block; wave w owns 16 compacted q rows. BK=32.
// S^T frag: lane holds S[q=lane&15][key = k0+rt*16+4*(lane>>4)+i].
__global__ __launch_bounds__(256, 3) void flash_fused(
    const u16* __restrict__ v1h, const u16* __restrict__ v1l,
    const u16* __restrict__ v2h, const u16* __restrict__ v2l,
    const u16* __restrict__ v1t, const u16* __restrict__ v2t,
    const int* __restrict__ cm1, const int* __restrict__ cm2,
    const int* __restrict__ qidx1, const int* __restrict__ qcnt1,
    const int* __restrict__ qidx2, const int* __restrict__ qcnt2,
    float* __restrict__ out)
{
    int i = blockIdx.x;
    int strm = i & 7;
    int j = i >> 3;
    int qt  = j & 15;
    int dir = (j >> 4) & 1;
    int b   = (j >> 5) * 8 + strm;

    const u16 *qh_g, *ql_g, *kh_g, *kl_g, *vt_g;
    const int *kmask, *qidx, *qcnt;
    float* ob;
    if (dir == 0) { qh_g=v1h; ql_g=v1l; kh_g=v2h; kl_g=v2l; vt_g=v2t;
                    kmask=cm2; qidx=qidx1; qcnt=qcnt1; ob=out; }
    else          { qh_g=v2h; ql_g=v2l; kh_g=v1h; kl_g=v1l; vt_g=v1t;
                    kmask=cm1; qidx=qidx2; qcnt=qcnt2; ob=out+ELEMS; }

    int cnt = qcnt[b];
    if (qt * BQ >= cnt) return;

    int tid = threadIdx.x;
    int w = tid >> 6, lane = tid & 63;
    int lq = lane & 15, g = lane >> 4;

    __shared__ __align__(16) u16 khi_s[BK * DD];  // [key][d], 16B chunks ^ (key&7)
    __shared__ __align__(16) u16 klo_s[BK * DD];
    __shared__ __align__(16) u16 vt_s[DD * BK];   // [d][key], chunk ^ (d&3)^((d>>2)&3)

    int qslot = qt * BQ + w * 16 + lq;
    bool qvalid = qslot < cnt;
    int qrow = qvalid ? qidx[b * LL + qslot] : 0;

    // Q fragments (B-operand): lane holds Q[q=lq][d = ks*32 + g*8 + j]
    const u16* qbh = qh_g + ((size_t)b * LL + qrow) * DD + g * 8;
    const u16* qbl = ql_g + ((size_t)b * LL + qrow) * DD + g * 8;
    short8 qhf[8], qlf[8];
#pragma unroll
    for (int ks = 0; ks < 8; ++ks) {
        qhf[ks] = *(const short8*)(qbh + ks * 32);
        qlf[ks] = *(const short8*)(qbl + ks * 32);
    }

    float m = MASK_FILL, z = 0.f;
    f32x4 o[16];
#pragma unroll
    for (int i2 = 0; i2 < 16; ++i2) o[i2] = (f32x4){0.f, 0.f, 0.f, 0.f};

    const size_t kv_base = (size_t)b * LL * DD;
    const size_t vt_base = (size_t)b * DD * LL;
    const int*  kmask_b = kmask + b * LL;
    const int pvcc = (g ^ (lq & 3) ^ ((lq >> 2) & 3)) * 8;   // VT chunk (hoisted)

    for (int kt = 0; kt < NKT; ++kt) {
        int k0 = kt * BK;
        __syncthreads();
        // stage K hi/lo + V^T via global_load_lds (linear LDS dest, pre-swizzled src)
#pragma unroll
        for (int jj = 0; jj < 4; ++jj) {
            int n = w * 4 + jj;
            unsigned phys = (unsigned)n * 1024u + (unsigned)lane * 16u;
            unsigned key = phys >> 9;
            unsigned cl = ((phys >> 4) & 31u) ^ (key & 7u);
            size_t koff = kv_base + (size_t)(k0 + (int)key) * DD + cl * 8;
            __builtin_amdgcn_global_load_lds(
                (const __attribute__((address_space(1))) void*)(kh_g + koff),
                (__attribute__((address_space(3))) void*)(&khi_s[n * 512]), 16, 0, 0);
            __builtin_amdgcn_global_load_lds(
                (const __attribute__((address_space(1))) void*)(kl_g + koff),
                (__attribute__((address_space(3))) void*)(&klo_s[n * 512]), 16, 0, 0);
            unsigned dv = (unsigned)n * 16u + ((unsigned)lane >> 2);
            unsigned cv = ((unsigned)lane & 3u) ^ (dv & 3u) ^ ((dv >> 2) & 3u);
            size_t voff = vt_base + (size_t)dv * LL + (unsigned)k0 + cv * 8;
            __builtin_amdgcn_global_load_lds(
                (const __attribute__((address_space(1))) void*)(vt_g + voff),
                (__attribute__((address_space(3))) void*)(&vt_s[n * 512]), 16, 0, 0);
        }
        __syncthreads();

        // S^T = K @ Q^T, hi/lo split (3 passes), two 16-key row tiles
        f32x4 sa0 = (f32x4){0.f, 0.f, 0.f, 0.f};
        f32x4 sa1 = (f32x4){0.f, 0.f, 0.f, 0.f};
#pragma unroll
        for (int ks = 0; ks < 8; ++ks) {
            int cidx = ((ks * 4 + g) ^ (lq & 7)) * 8;
            short8 kh0 = *(const short8*)&khi_s[lq * 256 + cidx];
            short8 kl0 = *(const short8*)&klo_s[lq * 256 + cidx];
            short8 kh1 = *(const short8*)&khi_s[(16 + lq) * 256 + cidx];
            short8 kl1 = *(const short8*)&klo_s[(16 + lq) * 256 + cidx];
            sa0 = __builtin_amdgcn_mfma_f32_16x16x32_bf16(kh0, qhf[ks], sa0, 0, 0, 0);
            sa0 = __builtin_amdgcn_mfma_f32_16x16x32_bf16(kh0, qlf[ks], sa0, 0, 0, 0);
            sa0 = __builtin_amdgcn_mfma_f32_16x16x32_bf16(kl0, qhf[ks], sa0, 0, 0, 0);
            sa1 = __builtin_amdgcn_mfma_f32_16x16x32_bf16(kh1, qhf[ks], sa1, 0, 0, 0);
            sa1 = __builtin_amdgcn_mfma_f32_16x16x32_bf16(kh1, qlf[ks], sa1, 0, 0, 0);
            sa1 = __builtin_amdgcn_mfma_f32_16x16x32_bf16(kl1, qhf[ks], sa1, 0, 0, 0);
        }

        // mask + online softmax (per-lane column q)
        int4v mk0 = *(const int4v*)&kmask_b[k0 + 4 * g];
        int4v mk1 = *(const int4v*)&kmask_b[k0 + 16 + 4 * g];
        float s[8];
#pragma unroll
        for (int i2 = 0; i2 < 4; ++i2) {
            s[i2]     = mk0[i2] ? MASK_FILL : sa0[i2];
            s[4 + i2] = mk1[i2] ? MASK_FILL : sa1[i2];
        }
        float pmax = s[0];
#pragma unroll
        for (int i2 = 1; i2 < 8; ++i2) pmax = fmaxf(pmax, s[i2]);
        pmax = fmaxf(pmax, __shfl_xor(pmax, 16));
        pmax = fmaxf(pmax, __shfl_xor(pmax, 32));
        if (__any(pmax > m)) {          // exact deferred rescale
            float mnew = fmaxf(m, pmax);
            float alpha = __expf(m - mnew);
            z *= alpha;
#pragma unroll
            for (int i2 = 0; i2 < 16; ++i2) o[i2] *= alpha;
            m = mnew;
        }
        float p[8], ps = 0.f;
#pragma unroll
        for (int i2 = 0; i2 < 8; ++i2) { p[i2] = __expf(s[i2] - m); ps += p[i2]; }
        ps += __shfl_xor(ps, 16);
        ps += __shfl_xor(ps, 32);
        z += ps;

        // P -> PV B-fragment (keys 8g..8g+7 at q=lq), in-register exchange
        unsigned pk00 = bf16_rne(p[0]) | (bf16_rne(p[1]) << 16);
        unsigned pk01 = bf16_rne(p[2]) | (bf16_rne(p[3]) << 16);
        unsigned pk10 = bf16_rne(p[4]) | (bf16_rne(p[5]) << 16);
        unsigned pk11 = bf16_rne(p[6]) | (bf16_rne(p[7]) << 16);
        int srcA = ((lane & 16) << 1) | lq;   // group 2*(g&1), same q
        int srcB = srcA + 16;
        unsigned a00 = (unsigned)__shfl((int)pk00, srcA);
        unsigned a01 = (unsigned)__shfl((int)pk01, srcA);
        unsigned a10 = (unsigned)__shfl((int)pk10, srcA);
        unsigned a11 = (unsigned)__shfl((int)pk11, srcA);
        unsigned b00 = (unsigned)__shfl((int)pk00, srcB);
        unsigned b01 = (unsigned)__shfl((int)pk01, srcB);
        unsigned b10 = (unsigned)__shfl((int)pk10, srcB);
        unsigned b11 = (unsigned)__shfl((int)pk11, srcB);
        bool sel = (g >> 1) != 0;             // upper 16 keys use rt=1 packs
        union { unsigned u[4]; short8 v; } pf;
        pf.u[0] = sel ? a10 : a00;
        pf.u[1] = sel ? a11 : a01;
        pf.u[2] = sel ? b10 : b00;
        pf.u[3] = sel ? b11 : b01;

        // O^T += V^T @ P^T  (A = V^T rows d, B = P^T)
#pragma unroll
        for (int dt = 0; dt < 16; ++dt) {
            int d = dt * 16 + lq;
            short8 vf = *(const short8*)&vt_s[d * 32 + pvcc];
            o[dt] = __builtin_amdgcn_mfma_f32_16x16x32_bf16(vf, pf.v, o[dt], 0, 0, 0);
        }
    }

    if (qvalid) {
        float zinv = 1.0f / z;
        float* orow = ob + ((size_t)b * LL + qrow) * DD + 4 * g;
#pragma unroll
        for (int dt = 0; dt < 16; ++dt) {
            f32x4 vv = o[dt] * zinv;
            *(f32x4*)(orow + dt * 16) = vv;
        }
    }
}

extern "C" void kernel_launch(void* const* d_in, const int* in_sizes, int n_in,
                              void* d_out, int out_size, void* d_ws, size_t ws_size,
                              hipStream_t stream)
{
    const float* v1      = (const float*)d_in[0];
    const void*  v1_mask = d_in[1];
    const float* v2      = (const float*)d_in[2];
    const void*  v2_mask = d_in[3];
    float* out = (float*)d_out;

    u16* v1h = (u16*)d_ws;
    u16* v1l = v1h + ELEMS;
    u16* v2h = v1l + ELEMS;
    u16* v2l = v2h + ELEMS;
    u16* v1t = v2l + ELEMS;
    u16* v2t = v1t + ELEMS;
    int* qidx1 = (int*)(v2t + ELEMS);
    int* qcnt1 = qidx1 + NB * LL;
    int* qidx2 = qcnt1 + NB;
    int* qcnt2 = qidx2 + NB * LL;
    int* cm1   = qcnt2 + NB;          // canonical int32 masks
    int* cm2   = cm1 + NB * LL;
    int* mflag = cm2 + NB * LL;
    // ws requirement: 6*ELEMS*2 + ~1.3 MB of int scratch ~= 203 MB

    mask_detect<<<dim3(1), dim3(256), 0, stream>>>(
        (const unsigned*)v1_mask, (const unsigned*)v2_mask, mflag);
    mask_convert<<<dim3(NB * LL / 256), dim3(256), 0, stream>>>(v1_mask, mflag, cm1);
    mask_convert<<<dim3(NB * LL / 256), dim3(256), 0, stream>>>(v2_mask, mflag, cm2);

    zero_rows<<<dim3(2 * NB * LL / 8), dim3(256), 0, stream>>>(cm1, cm2, out);
    prep2_kernel<<<dim3(2 * NB * 64), dim3(256), 0, stream>>>(
        v1, v1h, v1l, v1t, v2, v2h, v2l, v2t);
    build_qidx<<<dim3(NB), dim3(256), 0, stream>>>(cm1, qidx1, qcnt1);
    build_qidx<<<dim3(NB), dim3(256), 0, stream>>>(cm2, qidx2, qcnt2);

    // both directions in one launch; XCD-aware block mapping inside
    flash_fused<<<dim3(2 * NB * 16), dim3(256), 0, stream>>>(
        v1h, v1l, v2h, v2l, v1t, v2t, cm1, cm2,
        qidx1, qcnt1, qidx2, qcnt2, out);
}

// Round 4
// 466.069 us; speedup vs baseline: 1.2552x; 1.2552x over previous
//
#include <hip/hip_runtime.h>
#include <hip/hip_bf16.h>
#include <stdint.h>

// BidirectionalAttention2: two flash-attention passes over sim = v1 @ v2^T.
//  dir A: out1[l] = softmax_m(v2_mask ? -1e-7 : sim[l,m]) @ v2, rows zeroed by v1_mask
//  dir B: out2[m] = softmax_l(v1_mask ? -1e-7 : sim[l,m]) @ v1, rows zeroed by v2_mask
// Swapped-QK^T (S^T = mfma(K,Q)) + in-register online softmax, hi/lo bf16 split
// for the sim GEMM (3 mfma passes), query compaction.
// R4: 2-phase pipeline (T3-minimum): double-buffered 96KB LDS K/V staging,
//     global_load_lds for tile t+1 issued BEFORE compute of tile t, single
//     __syncthreads()/step as the vmcnt drain (loads hide under ~3k cyc of
//     compute). Block widened to 8 waves (BQ=128, 512 thr, 1 block/CU).

#define MASK_FILL -1e-07f

typedef unsigned short u16;
typedef __attribute__((ext_vector_type(8))) short short8;
typedef __attribute__((ext_vector_type(4))) float f32x4;
typedef __attribute__((ext_vector_type(4))) int int4v;
typedef __attribute__((ext_vector_type(4))) u16 u16x4;

#define NB 64
#define LL 1024
#define DD 256
#define BQ 128
#define BK 32
#define NKT (LL / BK)
#define ELEMS ((size_t)NB * LL * DD)

__device__ __forceinline__ unsigned bf16_rne(float f) {
    unsigned u = __float_as_uint(f);
    return (u + 0x7fffu + ((u >> 16) & 1u)) >> 16;
}

__device__ __forceinline__ void gll16(const u16* g, u16* l) {
    __builtin_amdgcn_global_load_lds(
        (const __attribute__((address_space(1))) void*)g,
        (__attribute__((address_space(3))) void*)l, 16, 0, 0);
}

// ---- mask dtype detection + normalization ----------------------------------
__global__ __launch_bounds__(256) void mask_detect(
    const unsigned* __restrict__ m1, const unsigned* __restrict__ m2,
    int* __restrict__ flag)
{
    unsigned acc = 0;
    for (int i = threadIdx.x; i < 4096; i += 256)
        acc |= (m1[i] | m2[i]) & ~1u;
    __shared__ unsigned red[256];
    red[threadIdx.x] = acc;
    __syncthreads();
    for (int o = 128; o; o >>= 1) {
        if (threadIdx.x < o) red[threadIdx.x] |= red[threadIdx.x + o];
        __syncthreads();
    }
    if (threadIdx.x == 0) *flag = red[0] ? 1 : 0;
}

__global__ __launch_bounds__(256) void mask_convert(
    const void* __restrict__ m, const int* __restrict__ flag,
    int* __restrict__ outm)
{
    int i = blockIdx.x * 256 + threadIdx.x;
    int v;
    if (*flag) v = ((const unsigned char*)m)[i];   // 1-byte bool path
    else       v = ((const int*)m)[i];             // int32 path
    outm[i] = v ? 1 : 0;
}

// ---- zero only the masked output rows ---------------------------------------
__global__ __launch_bounds__(256) void zero_rows(
    const int* __restrict__ cm1, const int* __restrict__ cm2,
    float* __restrict__ out)
{
    int r = blockIdx.x * 8 + (threadIdx.x >> 5);
    int c = (threadIdx.x & 31) * 8;
    int m = (r < NB * LL) ? cm1[r] : cm2[r - NB * LL];
    if (m) {
        f32x4 z4 = {0.f, 0.f, 0.f, 0.f};
        *(f32x4*)(out + (size_t)r * DD + c) = z4;
        *(f32x4*)(out + (size_t)r * DD + c + 4) = z4;
    }
}

// ---- pre-pass: fp32 -> (hi, lo) bf16 split + bf16 transpose, both tensors ---
__global__ __launch_bounds__(256) void prep2_kernel(
    const float* __restrict__ x1, u16* __restrict__ h1, u16* __restrict__ l1,
    u16* __restrict__ t1,
    const float* __restrict__ x2, u16* __restrict__ h2, u16* __restrict__ l2,
    u16* __restrict__ t2)
{
    __shared__ u16 t[64][65];
    int blk = blockIdx.x;
    int tensor = blk >> 12;
    blk &= 4095;
    const float* x = tensor ? x2 : x1;
    u16* h  = tensor ? h2 : h1;
    u16* lo = tensor ? l2 : l1;
    u16* xt = tensor ? t2 : t1;
    int b = blk >> 6, lt = (blk >> 2) & 15, dt = blk & 3;
    int l0 = lt * 64, d0 = dt * 64;
    int tid = threadIdx.x;
    int sub = tid >> 4;
    int c16 = tid & 15;
#pragma unroll
    for (int p = 0; p < 4; ++p) {
        int row = p * 16 + sub;
        size_t gi = ((size_t)b * LL + l0 + row) * DD + d0 + c16 * 4;
        f32x4 v = *(const f32x4*)(x + gi);
        u16x4 hv, lv;
#pragma unroll
        for (int e = 0; e < 4; ++e) {
            unsigned hb = bf16_rne(v[e]);
            float hf = __uint_as_float(hb << 16);
            unsigned lb = bf16_rne(v[e] - hf);
            hv[e] = (u16)hb;
            lv[e] = (u16)lb;
            t[c16 * 4 + e][row] = (u16)hb;
        }
        *(u16x4*)(h + gi) = hv;
        *(u16x4*)(lo + gi) = lv;
    }
    __syncthreads();
#pragma unroll
    for (int p = 0; p < 4; ++p) {
        int d = p * 16 + sub;
        u16x4 ov;
#pragma unroll
        for (int e = 0; e < 4; ++e) ov[e] = t[d][c16 * 4 + e];
        *(u16x4*)(xt + ((size_t)b * DD + d0 + d) * LL + l0 + c16 * 4) = ov;
    }
}

// ---- pre-pass: per-batch compaction of unmasked rows ------------------------
__global__ __launch_bounds__(256) void build_qidx(
    const int* __restrict__ mask, int* __restrict__ qidx, int* __restrict__ qcnt)
{
    int b = blockIdx.x, tid = threadIdx.x;
    __shared__ int ps[256];
    const int* mb = mask + b * LL;
    int f[4], s = 0;
#pragma unroll
    for (int j = 0; j < 4; ++j) { f[j] = (mb[tid * 4 + j] == 0) ? 1 : 0; s += f[j]; }
    ps[tid] = s;
    __syncthreads();
    for (int off = 1; off < 256; off <<= 1) {
        int v = (tid >= off) ? ps[tid - off] : 0;
        __syncthreads();
        ps[tid] += v;
        __syncthreads();
    }
    int pos = (tid > 0) ? ps[tid - 1] : 0;
#pragma unroll
    for (int j = 0; j < 4; ++j)
        if (f[j]) qidx[b * LL + (pos++)] = tid * 4 + j;
    if (tid == 255) qcnt[b] = ps[255];
}

// ---- fused bidirectional flash attention, 2-phase double-buffered -----------
// grid 1024: i%8 = XCD stream -> b%8; j=i>>3: qt(8) fastest, dir(2), b-octet(8).
// 8 waves/block; wave w owns 16 compacted q rows (BQ=128). BK=32 keys/step.
// S^T frag: lane holds S[q=lane&15][key = k0+rt*16+4*(lane>>4)+i].
__global__ __launch_bounds__(512, 1) void flash_fused(
    const u16* __restrict__ v1h, const u16* __restrict__ v1l,
    const u16* __restrict__ v2h, const u16* __restrict__ v2l,
    const u16* __restrict__ v1t, const u16* __restrict__ v2t,
    const int* __restrict__ cm1, const int* __restrict__ cm2,
    const int* __restrict__ qidx1, const int* __restrict__ qcnt1,
    const int* __restrict__ qidx2, const int* __restrict__ qcnt2,
    float* __restrict__ out)
{
    int i = blockIdx.x;
    int strm = i & 7;
    int j = i >> 3;
    int qt  = j & 7;
    int dir = (j >> 3) & 1;
    int b   = (j >> 4) * 8 + strm;

    const u16 *qh_g, *ql_g, *kh_g, *kl_g, *vt_g;
    const int *kmask, *qidx, *qcnt;
    float* ob;
    if (dir == 0) { qh_g=v1h; ql_g=v1l; kh_g=v2h; kl_g=v2l; vt_g=v2t;
                    kmask=cm2; qidx=qidx1; qcnt=qcnt1; ob=out; }
    else          { qh_g=v2h; ql_g=v2l; kh_g=v1h; kl_g=v1l; vt_g=v1t;
                    kmask=cm1; qidx=qidx2; qcnt=qcnt2; ob=out+ELEMS; }

    int cnt = qcnt[b];
    if (qt * BQ >= cnt) return;

    int tid = threadIdx.x;
    int w = tid >> 6, lane = tid & 63;
    int lq = lane & 15, g = lane >> 4;

    // double-buffered K/V staging: 2 x (16KB khi + 16KB klo + 16KB vt) = 96KB
    __shared__ __align__(16) u16 khi_s[2][BK * DD];  // [key][d], chunk ^ (key&7)
    __shared__ __align__(16) u16 klo_s[2][BK * DD];
    __shared__ __align__(16) u16 vt_s[2][DD * BK];   // [d][key], chunk ^ (d&3)^((d>>2)&3)

    int qslot = qt * BQ + w * 16 + lq;
    bool qvalid = qslot < cnt;
    int qrow = qvalid ? qidx[b * LL + qslot] : 0;

    // Q fragments (B-operand): lane holds Q[q=lq][d = ks*32 + g*8 + j]
    const u16* qbh = qh_g + ((size_t)b * LL + qrow) * DD + g * 8;
    const u16* qbl = ql_g + ((size_t)b * LL + qrow) * DD + g * 8;
    short8 qhf[8], qlf[8];
#pragma unroll
    for (int ks = 0; ks < 8; ++ks) {
        qhf[ks] = *(const short8*)(qbh + ks * 32);
        qlf[ks] = *(const short8*)(qbl + ks * 32);
    }

    float m = MASK_FILL, z = 0.f;
    f32x4 o[16];
#pragma unroll
    for (int i2 = 0; i2 < 16; ++i2) o[i2] = (f32x4){0.f, 0.f, 0.f, 0.f};

    const size_t kv_base = (size_t)b * LL * DD;
    const size_t vt_base = (size_t)b * DD * LL;
    const int*  kmask_b = kmask + b * LL;
    const int pvcc = (g ^ (lq & 3) ^ ((lq >> 2) & 3)) * 8;   // VT chunk (hoisted)

    // stage(buf, kt): 48 x 1KB global_load_lds units, 6 per wave
    // units: 0..15 khi (2 key-rows each), 16..31 klo, 32..47 vt (16 d-rows each)
#define STAGE(BUF, KT)                                                          \
    {                                                                           \
        int k0s = (KT) * BK;                                                    \
        _Pragma("unroll")                                                       \
        for (int t = 0; t < 6; ++t) {                                           \
            int u = t * 8 + w;                                                  \
            int n = u & 15;                                                     \
            if (u < 32) {                                                       \
                unsigned phys = (unsigned)n * 1024u + (unsigned)lane * 16u;     \
                unsigned key = phys >> 9;                                       \
                unsigned cl = ((phys >> 4) & 31u) ^ (key & 7u);                 \
                size_t koff = kv_base + (size_t)(k0s + (int)key) * DD + cl * 8; \
                if (u < 16) gll16(kh_g + koff, &khi_s[BUF][n * 512]);           \
                else        gll16(kl_g + koff, &klo_s[BUF][n * 512]);           \
            } else {                                                            \
                unsigned dv = (unsigned)n * 16u + ((unsigned)lane >> 2);        \
                unsigned cv = ((unsigned)lane & 3u) ^ (dv & 3u) ^ ((dv >> 2) & 3u); \
                size_t voff = vt_base + (size_t)dv * LL + (unsigned)k0s + cv * 8;   \
                gll16(vt_g + voff, &vt_s[BUF][n * 512]);                        \
            }                                                                   \
        }                                                                       \
    }

    STAGE(0, 0);
    __syncthreads();           // drains vmcnt(0): buf0 ready
    int cur = 0;

    for (int kt = 0; kt < NKT; ++kt) {
        int k0 = kt * BK;
        if (kt + 1 < NKT) STAGE(cur ^ 1, kt + 1);   // prefetch next tile

        // S^T = K @ Q^T, hi/lo split (3 passes), two 16-key row tiles
        f32x4 sa0 = (f32x4){0.f, 0.f, 0.f, 0.f};
        f32x4 sa1 = (f32x4){0.f, 0.f, 0.f, 0.f};
#pragma unroll
        for (int ks = 0; ks < 8; ++ks) {
            int cidx = ((ks * 4 + g) ^ (lq & 7)) * 8;
            short8 kh0 = *(const short8*)&khi_s[cur][lq * 256 + cidx];
            short8 kl0 = *(const short8*)&klo_s[cur][lq * 256 + cidx];
            short8 kh1 = *(const short8*)&khi_s[cur][(16 + lq) * 256 + cidx];
            short8 kl1 = *(const short8*)&klo_s[cur][(16 + lq) * 256 + cidx];
            sa0 = __builtin_amdgcn_mfma_f32_16x16x32_bf16(kh0, qhf[ks], sa0, 0, 0, 0);
            sa0 = __builtin_amdgcn_mfma_f32_16x16x32_bf16(kh0, qlf[ks], sa0, 0, 0, 0);
            sa0 = __builtin_amdgcn_mfma_f32_16x16x32_bf16(kl0, qhf[ks], sa0, 0, 0, 0);
            sa1 = __builtin_amdgcn_mfma_f32_16x16x32_bf16(kh1, qhf[ks], sa1, 0, 0, 0);
            sa1 = __builtin_amdgcn_mfma_f32_16x16x32_bf16(kh1, qlf[ks], sa1, 0, 0, 0);
            sa1 = __builtin_amdgcn_mfma_f32_16x16x32_bf16(kl1, qhf[ks], sa1, 0, 0, 0);
        }

        // mask + online softmax (per-lane column q)
        int4v mk0 = *(const int4v*)&kmask_b[k0 + 4 * g];
        int4v mk1 = *(const int4v*)&kmask_b[k0 + 16 + 4 * g];
        float s[8];
#pragma unroll
        for (int i2 = 0; i2 < 4; ++i2) {
            s[i2]     = mk0[i2] ? MASK_FILL : sa0[i2];
            s[4 + i2] = mk1[i2] ? MASK_FILL : sa1[i2];
        }
        float pmax = s[0];
#pragma unroll
        for (int i2 = 1; i2 < 8; ++i2) pmax = fmaxf(pmax, s[i2]);
        pmax = fmaxf(pmax, __shfl_xor(pmax, 16));
        pmax = fmaxf(pmax, __shfl_xor(pmax, 32));
        if (__any(pmax > m)) {          // exact deferred rescale
            float mnew = fmaxf(m, pmax);
            float alpha = __expf(m - mnew);
            z *= alpha;
#pragma unroll
            for (int i2 = 0; i2 < 16; ++i2) o[i2] *= alpha;
            m = mnew;
        }
        float p[8], ps = 0.f;
#pragma unroll
        for (int i2 = 0; i2 < 8; ++i2) { p[i2] = __expf(s[i2] - m); ps += p[i2]; }
        ps += __shfl_xor(ps, 16);
        ps += __shfl_xor(ps, 32);
        z += ps;

        // P -> PV B-fragment (keys 8g..8g+7 at q=lq), in-register exchange
        unsigned pk00 = bf16_rne(p[0]) | (bf16_rne(p[1]) << 16);
        unsigned pk01 = bf16_rne(p[2]) | (bf16_rne(p[3]) << 16);
        unsigned pk10 = bf16_rne(p[4]) | (bf16_rne(p[5]) << 16);
        unsigned pk11 = bf16_rne(p[6]) | (bf16_rne(p[7]) << 16);
        int srcA = ((lane & 16) << 1) | lq;   // group 2*(g&1), same q
        int srcB = srcA + 16;
        unsigned a00 = (unsigned)__shfl((int)pk00, srcA);
        unsigned a01 = (unsigned)__shfl((int)pk01, srcA);
        unsigned a10 = (unsigned)__shfl((int)pk10, srcA);
        unsigned a11 = (unsigned)__shfl((int)pk11, srcA);
        unsigned b00 = (unsigned)__shfl((int)pk00, srcB);
        unsigned b01 = (unsigned)__shfl((int)pk01, srcB);
        unsigned b10 = (unsigned)__shfl((int)pk10, srcB);
        unsigned b11 = (unsigned)__shfl((int)pk11, srcB);
        bool sel = (g >> 1) != 0;             // upper 16 keys use rt=1 packs
        union { unsigned u[4]; short8 v; } pf;
        pf.u[0] = sel ? a10 : a00;
        pf.u[1] = sel ? a11 : a01;
        pf.u[2] = sel ? b10 : b00;
        pf.u[3] = sel ? b11 : b01;

        // O^T += V^T @ P^T  (A = V^T rows d, B = P^T)
#pragma unroll
        for (int dt = 0; dt < 16; ++dt) {
            int d = dt * 16 + lq;
            short8 vf = *(const short8*)&vt_s[cur][d * 32 + pvcc];
            o[dt] = __builtin_amdgcn_mfma_f32_16x16x32_bf16(vf, pf.v, o[dt], 0, 0, 0);
        }

        __syncthreads();        // drains vmcnt(0): next buffer staged & ready
        cur ^= 1;
    }

    if (qvalid) {
        float zinv = 1.0f / z;
        float* orow = ob + ((size_t)b * LL + qrow) * DD + 4 * g;
#pragma unroll
        for (int dt = 0; dt < 16; ++dt) {
            f32x4 vv = o[dt] * zinv;
            *(f32x4*)(orow + dt * 16) = vv;
        }
    }
}

extern "C" void kernel_launch(void* const* d_in, const int* in_sizes, int n_in,
                              void* d_out, int out_size, void* d_ws, size_t ws_size,
                              hipStream_t stream)
{
    const float* v1      = (const float*)d_in[0];
    const void*  v1_mask = d_in[1];
    const float* v2      = (const float*)d_in[2];
    const void*  v2_mask = d_in[3];
    float* out = (float*)d_out;

    u16* v1h = (u16*)d_ws;
    u16* v1l = v1h + ELEMS;
    u16* v2h = v1l + ELEMS;
    u16* v2l = v2h + ELEMS;
    u16* v1t = v2l + ELEMS;
    u16* v2t = v1t + ELEMS;
    int* qidx1 = (int*)(v2t + ELEMS);
    int* qcnt1 = qidx1 + NB * LL;
    int* qidx2 = qcnt1 + NB;
    int* qcnt2 = qidx2 + NB * LL;
    int* cm1   = qcnt2 + NB;          // canonical int32 masks
    int* cm2   = cm1 + NB * LL;
    int* mflag = cm2 + NB * LL;

    mask_detect<<<dim3(1), dim3(256), 0, stream>>>(
        (const unsigned*)v1_mask, (const unsigned*)v2_mask, mflag);
    mask_convert<<<dim3(NB * LL / 256), dim3(256), 0, stream>>>(v1_mask, mflag, cm1);
    mask_convert<<<dim3(NB * LL / 256), dim3(256), 0, stream>>>(v2_mask, mflag, cm2);

    zero_rows<<<dim3(2 * NB * LL / 8), dim3(256), 0, stream>>>(cm1, cm2, out);
    prep2_kernel<<<dim3(2 * NB * 64), dim3(256), 0, stream>>>(
        v1, v1h, v1l, v1t, v2, v2h, v2l, v2t);
    build_qidx<<<dim3(NB), dim3(256), 0, stream>>>(cm1, qidx1, qcnt1);
    build_qidx<<<dim3(NB), dim3(256), 0, stream>>>(cm2, qidx2, qcnt2);

    // both directions in one launch; XCD-aware block mapping inside
    flash_fused<<<dim3(2 * NB * 8), dim3(512), 0, stream>>>(
        v1h, v1l, v2h, v2l, v1t, v2t, cm1, cm2,
        qidx1, qcnt1, qidx2, qcnt2, out);
}

// Round 5
// 397.653 us; speedup vs baseline: 1.4712x; 1.1720x over previous
//
#include <hip/hip_runtime.h>
#include <hip/hip_bf16.h>
#include <stdint.h>

// BidirectionalAttention2: two flash-attention passes over sim = v1 @ v2^T.
//  dir A: out1[l] = softmax_m(v2_mask ? -1e-7 : sim[l,m]) @ v2, rows zeroed by v1_mask
//  dir B: out2[m] = softmax_l(v1_mask ? -1e-7 : sim[l,m]) @ v1, rows zeroed by v2_mask
// Swapped-QK^T (S^T = mfma(K,Q)) + in-register online softmax, hi/lo bf16 split
// for the sim GEMM (3 mfma passes), query compaction.
// R5: (1) counted-vmcnt depth-2 pipeline (T3/T4): triple-buffered 144KB LDS,
//     stage tile kt+2 each iter, s_waitcnt vmcnt(6) + raw s_barrier (never a
//     full drain in the loop); setprio(1) around MFMA clusters (T5).
//     (2) mask folded into K at prep time: masked K rows zeroed in hi/lo ws
//     (exp(0) vs exp(-1e-7) differs by 1e-7 << bf16 P error) -> no mask loads
//     or cndmask in the inner loop, and exactly 6 VMEM ops/wave/iter.

#define MASK_FILL -1e-07f

typedef unsigned short u16;
typedef __attribute__((ext_vector_type(8))) short short8;
typedef __attribute__((ext_vector_type(4))) float f32x4;
typedef __attribute__((ext_vector_type(4))) u16 u16x4;

#define NB 64
#define LL 1024
#define DD 256
#define BQ 128
#define BK 32
#define NKT (LL / BK)
#define ELEMS ((size_t)NB * LL * DD)

__device__ __forceinline__ unsigned bf16_rne(float f) {
    unsigned u = __float_as_uint(f);
    return (u + 0x7fffu + ((u >> 16) & 1u)) >> 16;
}

__device__ __forceinline__ void gll16(const u16* g, u16* l) {
    __builtin_amdgcn_global_load_lds(
        (const __attribute__((address_space(1))) void*)g,
        (__attribute__((address_space(3))) void*)l, 16, 0, 0);
}

// ---- mask dtype detection + normalization ----------------------------------
__global__ __launch_bounds__(256) void mask_detect(
    const unsigned* __restrict__ m1, const unsigned* __restrict__ m2,
    int* __restrict__ flag)
{
    unsigned acc = 0;
    for (int i = threadIdx.x; i < 4096; i += 256)
        acc |= (m1[i] | m2[i]) & ~1u;
    __shared__ unsigned red[256];
    red[threadIdx.x] = acc;
    __syncthreads();
    for (int o = 128; o; o >>= 1) {
        if (threadIdx.x < o) red[threadIdx.x] |= red[threadIdx.x + o];
        __syncthreads();
    }
    if (threadIdx.x == 0) *flag = red[0] ? 1 : 0;
}

__global__ __launch_bounds__(256) void mask_convert(
    const void* __restrict__ m, const int* __restrict__ flag,
    int* __restrict__ outm)
{
    int i = blockIdx.x * 256 + threadIdx.x;
    int v;
    if (*flag) v = ((const unsigned char*)m)[i];   // 1-byte bool path
    else       v = ((const int*)m)[i];             // int32 path
    outm[i] = v ? 1 : 0;
}

// ---- zero only the masked output rows ---------------------------------------
__global__ __launch_bounds__(256) void zero_rows(
    const int* __restrict__ cm1, const int* __restrict__ cm2,
    float* __restrict__ out)
{
    int r = blockIdx.x * 8 + (threadIdx.x >> 5);
    int c = (threadIdx.x & 31) * 8;
    int m = (r < NB * LL) ? cm1[r] : cm2[r - NB * LL];
    if (m) {
        f32x4 z4 = {0.f, 0.f, 0.f, 0.f};
        *(f32x4*)(out + (size_t)r * DD + c) = z4;
        *(f32x4*)(out + (size_t)r * DD + c + 4) = z4;
    }
}

// ---- pre-pass: fp32 -> (hi,lo) bf16 split (K-masked) + bf16 transpose -------
// h/lo outputs are zeroed on masked rows (K role; Q role never reads masked
// rows thanks to compaction). xt (V role) keeps unmasked values.
__global__ __launch_bounds__(256) void prep2_kernel(
    const float* __restrict__ x1, u16* __restrict__ h1, u16* __restrict__ l1,
    u16* __restrict__ t1, const int* __restrict__ cmA,
    const float* __restrict__ x2, u16* __restrict__ h2, u16* __restrict__ l2,
    u16* __restrict__ t2, const int* __restrict__ cmB)
{
    __shared__ u16 t[64][65];
    int blk = blockIdx.x;
    int tensor = blk >> 12;
    blk &= 4095;
    const float* x = tensor ? x2 : x1;
    u16* h  = tensor ? h2 : h1;
    u16* lo = tensor ? l2 : l1;
    u16* xt = tensor ? t2 : t1;
    const int* cm = tensor ? cmB : cmA;
    int b = blk >> 6, lt = (blk >> 2) & 15, dt = blk & 3;
    int l0 = lt * 64, d0 = dt * 64;
    int tid = threadIdx.x;
    int sub = tid >> 4;
    int c16 = tid & 15;
#pragma unroll
    for (int p = 0; p < 4; ++p) {
        int row = p * 16 + sub;
        int masked = cm[b * LL + l0 + row];
        size_t gi = ((size_t)b * LL + l0 + row) * DD + d0 + c16 * 4;
        f32x4 v = *(const f32x4*)(x + gi);
        u16x4 hv, lv;
#pragma unroll
        for (int e = 0; e < 4; ++e) {
            unsigned hb = bf16_rne(v[e]);
            float hf = __uint_as_float(hb << 16);
            unsigned lb = bf16_rne(v[e] - hf);
            hv[e] = masked ? (u16)0 : (u16)hb;
            lv[e] = masked ? (u16)0 : (u16)lb;
            t[c16 * 4 + e][row] = (u16)hb;     // V role: unmasked
        }
        *(u16x4*)(h + gi) = hv;
        *(u16x4*)(lo + gi) = lv;
    }
    __syncthreads();
#pragma unroll
    for (int p = 0; p < 4; ++p) {
        int d = p * 16 + sub;
        u16x4 ov;
#pragma unroll
        for (int e = 0; e < 4; ++e) ov[e] = t[d][c16 * 4 + e];
        *(u16x4*)(xt + ((size_t)b * DD + d0 + d) * LL + l0 + c16 * 4) = ov;
    }
}

// ---- pre-pass: per-batch compaction of unmasked rows ------------------------
__global__ __launch_bounds__(256) void build_qidx(
    const int* __restrict__ mask, int* __restrict__ qidx, int* __restrict__ qcnt)
{
    int b = blockIdx.x, tid = threadIdx.x;
    __shared__ int ps[256];
    const int* mb = mask + b * LL;
    int f[4], s = 0;
#pragma unroll
    for (int j = 0; j < 4; ++j) { f[j] = (mb[tid * 4 + j] == 0) ? 1 : 0; s += f[j]; }
    ps[tid] = s;
    __syncthreads();
    for (int off = 1; off < 256; off <<= 1) {
        int v = (tid >= off) ? ps[tid - off] : 0;
        __syncthreads();
        ps[tid] += v;
        __syncthreads();
    }
    int pos = (tid > 0) ? ps[tid - 1] : 0;
#pragma unroll
    for (int j = 0; j < 4; ++j)
        if (f[j]) qidx[b * LL + (pos++)] = tid * 4 + j;
    if (tid == 255) qcnt[b] = ps[255];
}

// ---- fused bidirectional flash attention, depth-2 counted-vmcnt pipeline ----
// grid 1024: i%8 = XCD stream -> b%8. 8 waves/block, wave owns 16 q (BQ=128).
// Triple-buffered K/V staging; per iter: stage kt+2 (6 gll/wave), compute kt,
// s_waitcnt vmcnt(6) (tile kt+1's loads are the oldest 6), s_barrier.
__global__ __launch_bounds__(512, 1) void flash_fused(
    const u16* __restrict__ v1h, const u16* __restrict__ v1l,
    const u16* __restrict__ v2h, const u16* __restrict__ v2l,
    const u16* __restrict__ v1t, const u16* __restrict__ v2t,
    const int* __restrict__ qidx1, const int* __restrict__ qcnt1,
    const int* __restrict__ qidx2, const int* __restrict__ qcnt2,
    float* __restrict__ out)
{
    int i = blockIdx.x;
    int strm = i & 7;
    int j = i >> 3;
    int qt  = j & 7;
    int dir = (j >> 3) & 1;
    int b   = (j >> 4) * 8 + strm;

    const u16 *qh_g, *ql_g, *kh_g, *kl_g, *vt_g;
    const int *qidx, *qcnt;
    float* ob;
    if (dir == 0) { qh_g=v1h; ql_g=v1l; kh_g=v2h; kl_g=v2l; vt_g=v2t;
                    qidx=qidx1; qcnt=qcnt1; ob=out; }
    else          { qh_g=v2h; ql_g=v2l; kh_g=v1h; kl_g=v1l; vt_g=v1t;
                    qidx=qidx2; qcnt=qcnt2; ob=out+ELEMS; }

    int cnt = qcnt[b];
    if (qt * BQ >= cnt) return;

    int tid = threadIdx.x;
    int w = tid >> 6, lane = tid & 63;
    int lq = lane & 15, g = lane >> 4;

    // triple-buffered staging: 3 x (16KB kh + 16KB kl + 16KB vt) = 144KB
    __shared__ __align__(16) u16 kh3[3][BK * DD];  // [key][d], chunk ^ (key&7)
    __shared__ __align__(16) u16 kl3[3][BK * DD];
    __shared__ __align__(16) u16 vt3[3][DD * BK];  // [d][key], chunk ^ (d&3)^((d>>2)&3)

    int qslot = qt * BQ + w * 16 + lq;
    bool qvalid = qslot < cnt;
    int qrow = qvalid ? qidx[b * LL + qslot] : 0;

    // Q fragments (B-operand): lane holds Q[q=lq][d = ks*32 + g*8 + j]
    const u16* qbh = qh_g + ((size_t)b * LL + qrow) * DD + g * 8;
    const u16* qbl = ql_g + ((size_t)b * LL + qrow) * DD + g * 8;
    short8 qhf[8], qlf[8];
#pragma unroll
    for (int ks = 0; ks < 8; ++ks) {
        qhf[ks] = *(const short8*)(qbh + ks * 32);
        qlf[ks] = *(const short8*)(qbl + ks * 32);
    }

    float m = MASK_FILL, z = 0.f;
    f32x4 o[16];
#pragma unroll
    for (int i2 = 0; i2 < 16; ++i2) o[i2] = (f32x4){0.f, 0.f, 0.f, 0.f};

    const size_t kv_base = (size_t)b * LL * DD;
    const size_t vt_base = (size_t)b * DD * LL;
    const int pvcc = (g ^ (lq & 3) ^ ((lq >> 2) & 3)) * 8;   // VT chunk (hoisted)

    // 48 x 1KB gll units/tile, 6 per wave: u=w,8+w: kh | 16+w,24+w: kl | 32+w,40+w: vt
#define STAGE(PKH, PKL, PVT, KT)                                                \
    {                                                                           \
        int k0s = (KT) * BK;                                                    \
        _Pragma("unroll")                                                       \
        for (int t = 0; t < 6; ++t) {                                           \
            int u = t * 8 + w;                                                  \
            int n = u & 15;                                                     \
            if (u < 32) {                                                       \
                unsigned phys = (unsigned)n * 1024u + (unsigned)lane * 16u;     \
                unsigned key = phys >> 9;                                       \
                unsigned cl = ((phys >> 4) & 31u) ^ (key & 7u);                 \
                size_t koff = kv_base + (size_t)(k0s + (int)key) * DD + cl * 8; \
                if (u < 16) gll16(kh_g + koff, (PKH) + n * 512);                \
                else        gll16(kl_g + koff, (PKL) + n * 512);                \
            } else {                                                            \
                unsigned dv = (unsigned)n * 16u + ((unsigned)lane >> 2);        \
                unsigned cv = ((unsigned)lane & 3u) ^ (dv & 3u) ^ ((dv >> 2) & 3u); \
                size_t voff = vt_base + (size_t)dv * LL + (unsigned)k0s + cv * 8;   \
                gll16(vt_g + voff, (PVT) + n * 512);                            \
            }                                                                   \
        }                                                                       \
    }

    u16 *khA = kh3[0], *khB = kh3[1], *khC = kh3[2];
    u16 *klA = kl3[0], *klB = kl3[1], *klC = kl3[2];
    u16 *vtA = vt3[0], *vtB = vt3[1], *vtC = vt3[2];

    STAGE(khA, klA, vtA, 0);
    STAGE(khB, klB, vtB, 1);
    asm volatile("s_waitcnt vmcnt(6)" ::: "memory");   // tile 0 landed
    __builtin_amdgcn_s_barrier();
    __builtin_amdgcn_sched_barrier(0);

    for (int kt = 0; kt < NKT; ++kt) {
        if (kt + 2 < NKT) STAGE(khC, klC, vtC, kt + 2);

        // S^T = K @ Q^T, hi/lo split (3 passes), two 16-key row tiles
        f32x4 sa0 = (f32x4){0.f, 0.f, 0.f, 0.f};
        f32x4 sa1 = (f32x4){0.f, 0.f, 0.f, 0.f};
        __builtin_amdgcn_s_setprio(1);
#pragma unroll
        for (int ks = 0; ks < 8; ++ks) {
            int cidx = ((ks * 4 + g) ^ (lq & 7)) * 8;
            short8 kh0 = *(const short8*)&khA[lq * 256 + cidx];
            short8 kl0 = *(const short8*)&klA[lq * 256 + cidx];
            short8 kh1 = *(const short8*)&khA[(16 + lq) * 256 + cidx];
            short8 kl1 = *(const short8*)&klA[(16 + lq) * 256 + cidx];
            sa0 = __builtin_amdgcn_mfma_f32_16x16x32_bf16(kh0, qhf[ks], sa0, 0, 0, 0);
            sa0 = __builtin_amdgcn_mfma_f32_16x16x32_bf16(kh0, qlf[ks], sa0, 0, 0, 0);
            sa0 = __builtin_amdgcn_mfma_f32_16x16x32_bf16(kl0, qhf[ks], sa0, 0, 0, 0);
            sa1 = __builtin_amdgcn_mfma_f32_16x16x32_bf16(kh1, qhf[ks], sa1, 0, 0, 0);
            sa1 = __builtin_amdgcn_mfma_f32_16x16x32_bf16(kh1, qlf[ks], sa1, 0, 0, 0);
            sa1 = __builtin_amdgcn_mfma_f32_16x16x32_bf16(kl1, qhf[ks], sa1, 0, 0, 0);
        }
        __builtin_amdgcn_s_setprio(0);

        // online softmax (per-lane column q); masked keys have s = 0 ~ -1e-7
        float s[8];
#pragma unroll
        for (int i2 = 0; i2 < 4; ++i2) { s[i2] = sa0[i2]; s[4 + i2] = sa1[i2]; }
        float pmax = s[0];
#pragma unroll
        for (int i2 = 1; i2 < 8; ++i2) pmax = fmaxf(pmax, s[i2]);
        pmax = fmaxf(pmax, __shfl_xor(pmax, 16));
        pmax = fmaxf(pmax, __shfl_xor(pmax, 32));
        if (__any(pmax > m)) {          // exact deferred rescale
            float mnew = fmaxf(m, pmax);
            float alpha = __expf(m - mnew);
            z *= alpha;
#pragma unroll
            for (int i2 = 0; i2 < 16; ++i2) o[i2] *= alpha;
            m = mnew;
        }
        float p[8], ps = 0.f;
#pragma unroll
        for (int i2 = 0; i2 < 8; ++i2) { p[i2] = __expf(s[i2] - m); ps += p[i2]; }
        ps += __shfl_xor(ps, 16);
        ps += __shfl_xor(ps, 32);
        z += ps;

        // P -> PV B-fragment (keys 8g..8g+7 at q=lq), in-register exchange
        unsigned pk00 = bf16_rne(p[0]) | (bf16_rne(p[1]) << 16);
        unsigned pk01 = bf16_rne(p[2]) | (bf16_rne(p[3]) << 16);
        unsigned pk10 = bf16_rne(p[4]) | (bf16_rne(p[5]) << 16);
        unsigned pk11 = bf16_rne(p[6]) | (bf16_rne(p[7]) << 16);
        int srcA = ((lane & 16) << 1) | lq;   // group 2*(g&1), same q
        int srcB = srcA + 16;
        unsigned a00 = (unsigned)__shfl((int)pk00, srcA);
        unsigned a01 = (unsigned)__shfl((int)pk01, srcA);
        unsigned a10 = (unsigned)__shfl((int)pk10, srcA);
        unsigned a11 = (unsigned)__shfl((int)pk11, srcA);
        unsigned b00 = (unsigned)__shfl((int)pk00, srcB);
        unsigned b01 = (unsigned)__shfl((int)pk01, srcB);
        unsigned b10 = (unsigned)__shfl((int)pk10, srcB);
        unsigned b11 = (unsigned)__shfl((int)pk11, srcB);
        bool sel = (g >> 1) != 0;             // upper 16 keys use rt=1 packs
        union { unsigned u[4]; short8 v; } pf;
        pf.u[0] = sel ? a10 : a00;
        pf.u[1] = sel ? a11 : a01;
        pf.u[2] = sel ? b10 : b00;
        pf.u[3] = sel ? b11 : b01;

        // O^T += V^T @ P^T  (A = V^T rows d, B = P^T)
        __builtin_amdgcn_s_setprio(1);
#pragma unroll
        for (int dt = 0; dt < 16; ++dt) {
            int d = dt * 16 + lq;
            short8 vf = *(const short8*)&vtA[d * 32 + pvcc];
            o[dt] = __builtin_amdgcn_mfma_f32_16x16x32_bf16(vf, pf.v, o[dt], 0, 0, 0);
        }
        __builtin_amdgcn_s_setprio(0);

        if (kt + 1 < NKT) {
            if (kt + 2 < NKT) {                               // tile kt+2 in flight
                asm volatile("s_waitcnt vmcnt(6)" ::: "memory");
            } else {                                          // nothing newer
                asm volatile("s_waitcnt vmcnt(0)" ::: "memory");
            }
            __builtin_amdgcn_s_barrier();
            __builtin_amdgcn_sched_barrier(0);
        }
        // rotate buffers: A <- B <- C <- A
        u16* tkh = khA; khA = khB; khB = khC; khC = tkh;
        u16* tkl = klA; klA = klB; klB = klC; klC = tkl;
        u16* tvt = vtA; vtA = vtB; vtB = vtC; vtC = tvt;
    }
#undef STAGE

    if (qvalid) {
        float zinv = 1.0f / z;
        float* orow = ob + ((size_t)b * LL + qrow) * DD + 4 * g;
#pragma unroll
        for (int dt = 0; dt < 16; ++dt) {
            f32x4 vv = o[dt] * zinv;
            *(f32x4*)(orow + dt * 16) = vv;
        }
    }
}

extern "C" void kernel_launch(void* const* d_in, const int* in_sizes, int n_in,
                              void* d_out, int out_size, void* d_ws, size_t ws_size,
                              hipStream_t stream)
{
    const float* v1      = (const float*)d_in[0];
    const void*  v1_mask = d_in[1];
    const float* v2      = (const float*)d_in[2];
    const void*  v2_mask = d_in[3];
    float* out = (float*)d_out;

    u16* v1h = (u16*)d_ws;
    u16* v1l = v1h + ELEMS;
    u16* v2h = v1l + ELEMS;
    u16* v2l = v2h + ELEMS;
    u16* v1t = v2l + ELEMS;
    u16* v2t = v1t + ELEMS;
    int* qidx1 = (int*)(v2t + ELEMS);
    int* qcnt1 = qidx1 + NB * LL;
    int* qidx2 = qcnt1 + NB;
    int* qcnt2 = qidx2 + NB * LL;
    int* cm1   = qcnt2 + NB;          // canonical int32 masks
    int* cm2   = cm1 + NB * LL;
    int* mflag = cm2 + NB * LL;

    mask_detect<<<dim3(1), dim3(256), 0, stream>>>(
        (const unsigned*)v1_mask, (const unsigned*)v2_mask, mflag);
    mask_convert<<<dim3(NB * LL / 256), dim3(256), 0, stream>>>(v1_mask, mflag, cm1);
    mask_convert<<<dim3(NB * LL / 256), dim3(256), 0, stream>>>(v2_mask, mflag, cm2);

    zero_rows<<<dim3(2 * NB * LL / 8), dim3(256), 0, stream>>>(cm1, cm2, out);
    prep2_kernel<<<dim3(2 * NB * 64), dim3(256), 0, stream>>>(
        v1, v1h, v1l, v1t, cm1, v2, v2h, v2l, v2t, cm2);
    build_qidx<<<dim3(NB), dim3(256), 0, stream>>>(cm1, qidx1, qcnt1);
    build_qidx<<<dim3(NB), dim3(256), 0, stream>>>(cm2, qidx2, qcnt2);

    // both directions in one launch; XCD-aware block mapping inside
    flash_fused<<<dim3(2 * NB * 8), dim3(512), 0, stream>>>(
        v1h, v1l, v2h, v2l, v1t, v2t,
        qidx1, qcnt1, qidx2, qcnt2, out);
}

// Round 6
// 273.160 us; speedup vs baseline: 2.1417x; 1.4558x over previous
//
#include <hip/hip_runtime.h>
#include <hip/hip_bf16.h>
#include <stdint.h>

// BidirectionalAttention2: two flash-attention passes over sim = v1 @ v2^T.
// R6: (1) EXACT masked-key lump: all masked keys have logit == MASK_FILL, so
//     flash runs only over compacted UNMASKED keys (~half), then adds
//     w=exp(MASK_FILL-m): z += nmask*w, o += w*Vsum_masked. Halves K-loop work.
//     (2) persistent 256 blocks + per-XCD work-steal counters (overflow steal
//     at tail) to kill the static-assignment imbalance (R5: 13.8% occ of 25%).
//     Pipeline from R5 kept: triple-buffered LDS, counted vmcnt(6), setprio.

#define MASK_FILL -1e-07f

typedef unsigned short u16;
typedef __attribute__((ext_vector_type(8))) short short8;
typedef __attribute__((ext_vector_type(4))) float f32x4;
typedef __attribute__((ext_vector_type(4))) u16 u16x4;

#define NB 64
#define LL 1024
#define DD 256
#define BQ 128
#define BK 32
#define ELEMS ((size_t)NB * LL * DD)
#define NIT_STREAM 128   // items per stream: qt(8) x dir(2) x boct(8)

__device__ __forceinline__ unsigned bf16_rne(float f) {
    unsigned u = __float_as_uint(f);
    return (u + 0x7fffu + ((u >> 16) & 1u)) >> 16;
}

__device__ __forceinline__ void gll16(const u16* g, u16* l) {
    __builtin_amdgcn_global_load_lds(
        (const __attribute__((address_space(1))) void*)g,
        (__attribute__((address_space(3))) void*)l, 16, 0, 0);
}

// ---- mask dtype detection + normalization ----------------------------------
__global__ __launch_bounds__(256) void mask_detect(
    const unsigned* __restrict__ m1, const unsigned* __restrict__ m2,
    int* __restrict__ flag)
{
    unsigned acc = 0;
    for (int i = threadIdx.x; i < 4096; i += 256)
        acc |= (m1[i] | m2[i]) & ~1u;
    __shared__ unsigned red[256];
    red[threadIdx.x] = acc;
    __syncthreads();
    for (int o = 128; o; o >>= 1) {
        if (threadIdx.x < o) red[threadIdx.x] |= red[threadIdx.x + o];
        __syncthreads();
    }
    if (threadIdx.x == 0) *flag = red[0] ? 1 : 0;
}

__global__ __launch_bounds__(256) void mask_convert(
    const void* __restrict__ m, const int* __restrict__ flag,
    int* __restrict__ outm)
{
    int i = blockIdx.x * 256 + threadIdx.x;
    int v;
    if (*flag) v = ((const unsigned char*)m)[i];
    else       v = ((const int*)m)[i];
    outm[i] = v ? 1 : 0;
}

// ---- zero only the masked output rows ---------------------------------------
__global__ __launch_bounds__(256) void zero_rows(
    const int* __restrict__ cm1, const int* __restrict__ cm2,
    float* __restrict__ out)
{
    int r = blockIdx.x * 8 + (threadIdx.x >> 5);
    int c = (threadIdx.x & 31) * 8;
    int m = (r < NB * LL) ? cm1[r] : cm2[r - NB * LL];
    if (m) {
        f32x4 z4 = {0.f, 0.f, 0.f, 0.f};
        *(f32x4*)(out + (size_t)r * DD + c) = z4;
        *(f32x4*)(out + (size_t)r * DD + c + 4) = z4;
    }
}

// ---- per-batch compaction: qidx (ordered unmasked rows), posAll, qcnt -------
__global__ __launch_bounds__(256) void build_qidx(
    const int* __restrict__ mask, int* __restrict__ qidx,
    int* __restrict__ posAll, int* __restrict__ qcnt)
{
    int b = blockIdx.x, tid = threadIdx.x;
    __shared__ int ps[256];
    const int* mb = mask + b * LL;
    int f[4], s = 0;
#pragma unroll
    for (int j = 0; j < 4; ++j) { f[j] = (mb[tid * 4 + j] == 0) ? 1 : 0; s += f[j]; }
    ps[tid] = s;
    __syncthreads();
    for (int off = 1; off < 256; off <<= 1) {
        int v = (tid >= off) ? ps[tid - off] : 0;
        __syncthreads();
        ps[tid] += v;
        __syncthreads();
    }
    int pos = (tid > 0) ? ps[tid - 1] : 0;
#pragma unroll
    for (int j = 0; j < 4; ++j) {
        posAll[b * LL + tid * 4 + j] = pos;
        if (f[j]) qidx[b * LL + (pos++)] = tid * 4 + j;
    }
    if (tid == 255) qcnt[b] = ps[255];
}

// ---- prep: fp32 -> (hi,lo) bf16 COMPACTED rows + compacted transpose + ------
// ---- deterministic per-tile masked-V partial sums ---------------------------
// grid: 2*NB*64 blocks (tensor, b, ltile(16), dtile(4)), 256 threads.
__global__ __launch_bounds__(256) void prep2_kernel(
    const float* __restrict__ x1, u16* __restrict__ h1, u16* __restrict__ l1,
    u16* __restrict__ t1, const int* __restrict__ cm1,
    const int* __restrict__ pa1, const int* __restrict__ qi1,
    const int* __restrict__ qc1,
    const float* __restrict__ x2, u16* __restrict__ h2, u16* __restrict__ l2,
    u16* __restrict__ t2, const int* __restrict__ cm2,
    const int* __restrict__ pa2, const int* __restrict__ qi2,
    const int* __restrict__ qc2,
    float* __restrict__ part)   // [2][NB][16][256]
{
    __shared__ u16 t[64][65];
    __shared__ float ps2[16][68];
    int blk = blockIdx.x;
    int tensor = blk >> 12;
    blk &= 4095;
    const float* x = tensor ? x2 : x1;
    u16* h  = tensor ? h2 : h1;
    u16* lo = tensor ? l2 : l1;
    u16* xt = tensor ? t2 : t1;
    const int* cm = tensor ? cm2 : cm1;
    const int* pa = tensor ? pa2 : pa1;
    const int* qi = tensor ? qi2 : qi1;
    const int* qc = tensor ? qc2 : qc1;
    int b = blk >> 6, lt = (blk >> 2) & 15, dt = blk & 3;
    int l0 = lt * 64, d0 = dt * 64;
    int tid = threadIdx.x;
    int sub = tid >> 4;
    int c16 = tid & 15;
    float vpart[4] = {0.f, 0.f, 0.f, 0.f};
#pragma unroll
    for (int p = 0; p < 4; ++p) {
        int row = p * 16 + sub;
        int l = l0 + row;
        int masked = cm[b * LL + l];
        int slot = pa[b * LL + l];
        f32x4 v = *(const f32x4*)(x + ((size_t)b * LL + l) * DD + d0 + c16 * 4);
        u16x4 hv, lv;
#pragma unroll
        for (int e = 0; e < 4; ++e) {
            unsigned hb = bf16_rne(v[e]);
            float hf = __uint_as_float(hb << 16);
            unsigned lb = bf16_rne(v[e] - hf);
            hv[e] = (u16)hb;
            lv[e] = (u16)lb;
            t[c16 * 4 + e][row] = (u16)hb;
            if (masked) vpart[e] += v[e];
        }
        if (!masked) {
            size_t gi = ((size_t)b * LL + slot) * DD + d0 + c16 * 4;
            *(u16x4*)(h + gi) = hv;
            *(u16x4*)(lo + gi) = lv;
        }
    }
#pragma unroll
    for (int e = 0; e < 4; ++e) ps2[sub][c16 * 4 + e] = vpart[e];
    __syncthreads();
    // compacted transpose: columns of this tile map to slots [pos_base, pos_base+nun)
    int pos_base = pa[b * LL + l0];
    int cntb = qc[b];
    int nun = ((lt == 15) ? cntb : pa[b * LL + l0 + 64]) - pos_base;
#pragma unroll
    for (int p = 0; p < 4; ++p) {
        int d = p * 16 + sub;
#pragma unroll
        for (int e = 0; e < 4; ++e) {
            int j = c16 * 4 + e;
            if (j < nun) {
                int col = qi[b * LL + pos_base + j] - l0;
                xt[((size_t)b * DD + d0 + d) * LL + pos_base + j] = t[d][col];
            }
        }
    }
    // deterministic masked-V partial: fixed-order sum over the 16 sub rows
    if (tid < 64) {
        float s = 0.f;
#pragma unroll
        for (int k = 0; k < 16; ++k) s += ps2[k][tid];
        part[(((size_t)tensor * NB + b) * 16 + lt) * 256 + d0 + tid] = s;
    }
}

// ---- reduce per-tile partials -> Vsum[tensor][b][256] (fixed order) ---------
__global__ __launch_bounds__(256) void vsum_reduce(
    const float* __restrict__ part, float* __restrict__ vsum)
{
    int blk = blockIdx.x;       // tensor*NB + b
    int d = threadIdx.x;
    float s = 0.f;
#pragma unroll
    for (int lt = 0; lt < 16; ++lt)
        s += part[((size_t)blk * 16 + lt) * 256 + d];
    vsum[(size_t)blk * DD + d] = s;
}

// ---- persistent fused flash, compacted keys, per-XCD work stealing ----------
// 256 blocks x 512 thr. stream = blockIdx&7 -> batches b%8 (XCD L2 locality);
// item it: qt=it&7, dir=(it>>3)&1, boct=it>>4. Overflow-steals other streams.
__global__ __launch_bounds__(512, 1) void flash_fused(
    const u16* __restrict__ v1h, const u16* __restrict__ v1l,
    const u16* __restrict__ v2h, const u16* __restrict__ v2l,
    const u16* __restrict__ v1t, const u16* __restrict__ v2t,
    const int* __restrict__ qidx1, const int* __restrict__ qcnt1,
    const int* __restrict__ qidx2, const int* __restrict__ qcnt2,
    const float* __restrict__ vsum, int* __restrict__ ctr,
    float* __restrict__ out)
{
    int strm0 = blockIdx.x & 7;
    int tid = threadIdx.x;
    int w = tid >> 6, lane = tid & 63;
    int lq = lane & 15, g = lane >> 4;

    __shared__ __align__(16) u16 kh3[3][BK * DD];  // [key][d], chunk ^ (key&7)
    __shared__ __align__(16) u16 kl3[3][BK * DD];
    __shared__ __align__(16) u16 vt3[3][DD * BK];  // [d][key], chunk ^ (d&3)^((d>>2)&3)
    __shared__ int sh_it;

    const int pvcc = (g ^ (lq & 3) ^ ((lq >> 2) & 3)) * 8;

#define STAGE(PKH, PKL, PVT, KT, KVB, VTB, KHG, KLG, VTG)                       \
    {                                                                           \
        int k0s = (KT) * BK;                                                    \
        _Pragma("unroll")                                                       \
        for (int t = 0; t < 6; ++t) {                                           \
            int u = t * 8 + w;                                                  \
            int n = u & 15;                                                     \
            if (u < 32) {                                                       \
                unsigned phys = (unsigned)n * 1024u + (unsigned)lane * 16u;     \
                unsigned key = phys >> 9;                                       \
                unsigned cl = ((phys >> 4) & 31u) ^ (key & 7u);                 \
                size_t koff = (KVB) + (size_t)(k0s + (int)key) * DD + cl * 8;   \
                if (u < 16) gll16((KHG) + koff, (PKH) + n * 512);               \
                else        gll16((KLG) + koff, (PKL) + n * 512);               \
            } else {                                                            \
                unsigned dv = (unsigned)n * 16u + ((unsigned)lane >> 2);        \
                unsigned cv = ((unsigned)lane & 3u) ^ (dv & 3u) ^ ((dv >> 2) & 3u); \
                size_t voff = (VTB) + (size_t)dv * LL + (unsigned)k0s + cv * 8; \
                gll16((VTG) + voff, (PVT) + n * 512);                           \
            }                                                                   \
        }                                                                       \
    }

    for (int ss = 0; ss < 8; ++ss) {
        int s2 = (strm0 + ss) & 7;
        for (;;) {
            __syncthreads();                       // protect sh_it reuse
            if (tid == 0) sh_it = atomicAdd(&ctr[s2], 1);
            __syncthreads();
            int it = sh_it;
            if (it >= NIT_STREAM) break;
            int qt  = it & 7;
            int dir = (it >> 3) & 1;
            int b   = ((it >> 4) << 3) + s2;

            const u16 *qh_g, *ql_g, *kh_g, *kl_g, *vt_g;
            const int *qidx, *qcq, *qck;
            const float* vsp;
            float* ob;
            if (dir == 0) { qh_g=v1h; ql_g=v1l; kh_g=v2h; kl_g=v2l; vt_g=v2t;
                            qidx=qidx1; qcq=qcnt1; qck=qcnt2;
                            vsp = vsum + ((size_t)NB + b) * DD; ob = out; }
            else          { qh_g=v2h; ql_g=v2l; kh_g=v1h; kl_g=v1l; vt_g=v1t;
                            qidx=qidx2; qcq=qcnt2; qck=qcnt1;
                            vsp = vsum + (size_t)b * DD; ob = out + ELEMS; }
            int cnt_q = qcq[b];
            if (qt * BQ >= cnt_q) continue;
            int cnt_k = qck[b];
            int nkt = (cnt_k + BK - 1) >> 5;

            int qslot = qt * BQ + w * 16 + lq;
            bool qvalid = qslot < cnt_q;

            // Q fragments from compacted rows (row == qslot)
            const u16* qbh = qh_g + ((size_t)b * LL + qslot) * DD + g * 8;
            const u16* qbl = ql_g + ((size_t)b * LL + qslot) * DD + g * 8;
            short8 qhf[8], qlf[8];
#pragma unroll
            for (int ks = 0; ks < 8; ++ks) {
                qhf[ks] = *(const short8*)(qbh + ks * 32);
                qlf[ks] = *(const short8*)(qbl + ks * 32);
            }

            float m = MASK_FILL, z = 0.f;
            f32x4 o[16];
#pragma unroll
            for (int i2 = 0; i2 < 16; ++i2) o[i2] = (f32x4){0.f, 0.f, 0.f, 0.f};

            const size_t kv_base = (size_t)b * LL * DD;
            const size_t vt_base = (size_t)b * DD * LL;

            if (nkt > 0) {
                u16 *khA = kh3[0], *khB = kh3[1], *khC = kh3[2];
                u16 *klA = kl3[0], *klB = kl3[1], *klC = kl3[2];
                u16 *vtA = vt3[0], *vtB = vt3[1], *vtC = vt3[2];

                STAGE(khA, klA, vtA, 0, kv_base, vt_base, kh_g, kl_g, vt_g);
                if (nkt > 1) {
                    STAGE(khB, klB, vtB, 1, kv_base, vt_base, kh_g, kl_g, vt_g);
                    asm volatile("s_waitcnt vmcnt(6)" ::: "memory");
                } else {
                    asm volatile("s_waitcnt vmcnt(0)" ::: "memory");
                }
                __builtin_amdgcn_s_barrier();
                __builtin_amdgcn_sched_barrier(0);

                for (int kt = 0; kt < nkt; ++kt) {
                    int k0 = kt * BK;
                    if (kt + 2 < nkt)
                        STAGE(khC, klC, vtC, kt + 2, kv_base, vt_base, kh_g, kl_g, vt_g);

                    f32x4 sa0 = (f32x4){0.f, 0.f, 0.f, 0.f};
                    f32x4 sa1 = (f32x4){0.f, 0.f, 0.f, 0.f};
                    __builtin_amdgcn_s_setprio(1);
#pragma unroll
                    for (int ks = 0; ks < 8; ++ks) {
                        int cidx = ((ks * 4 + g) ^ (lq & 7)) * 8;
                        short8 kh0 = *(const short8*)&khA[lq * 256 + cidx];
                        short8 kl0 = *(const short8*)&klA[lq * 256 + cidx];
                        short8 kh1 = *(const short8*)&khA[(16 + lq) * 256 + cidx];
                        short8 kl1 = *(const short8*)&klA[(16 + lq) * 256 + cidx];
                        sa0 = __builtin_amdgcn_mfma_f32_16x16x32_bf16(kh0, qhf[ks], sa0, 0, 0, 0);
                        sa0 = __builtin_amdgcn_mfma_f32_16x16x32_bf16(kh0, qlf[ks], sa0, 0, 0, 0);
                        sa0 = __builtin_amdgcn_mfma_f32_16x16x32_bf16(kl0, qhf[ks], sa0, 0, 0, 0);
                        sa1 = __builtin_amdgcn_mfma_f32_16x16x32_bf16(kh1, qhf[ks], sa1, 0, 0, 0);
                        sa1 = __builtin_amdgcn_mfma_f32_16x16x32_bf16(kh1, qlf[ks], sa1, 0, 0, 0);
                        sa1 = __builtin_amdgcn_mfma_f32_16x16x32_bf16(kl1, qhf[ks], sa1, 0, 0, 0);
                    }
                    __builtin_amdgcn_s_setprio(0);

                    float s[8];
#pragma unroll
                    for (int i2 = 0; i2 < 4; ++i2) { s[i2] = sa0[i2]; s[4 + i2] = sa1[i2]; }
                    if (kt == nkt - 1) {             // tail clamp: fake keys -> -inf
                        int base = k0 + 4 * g;
#pragma unroll
                        for (int i2 = 0; i2 < 4; ++i2) {
                            if (base + i2 >= cnt_k)      s[i2]     = -1e30f;
                            if (base + 16 + i2 >= cnt_k) s[4 + i2] = -1e30f;
                        }
                    }
                    float pmax = s[0];
#pragma unroll
                    for (int i2 = 1; i2 < 8; ++i2) pmax = fmaxf(pmax, s[i2]);
                    pmax = fmaxf(pmax, __shfl_xor(pmax, 16));
                    pmax = fmaxf(pmax, __shfl_xor(pmax, 32));
                    if (__any(pmax > m)) {
                        float mnew = fmaxf(m, pmax);
                        float alpha = __expf(m - mnew);
                        z *= alpha;
#pragma unroll
                        for (int i2 = 0; i2 < 16; ++i2) o[i2] *= alpha;
                        m = mnew;
                    }
                    float p[8], ps = 0.f;
#pragma unroll
                    for (int i2 = 0; i2 < 8; ++i2) { p[i2] = __expf(s[i2] - m); ps += p[i2]; }
                    ps += __shfl_xor(ps, 16);
                    ps += __shfl_xor(ps, 32);
                    z += ps;

                    unsigned pk00 = bf16_rne(p[0]) | (bf16_rne(p[1]) << 16);
                    unsigned pk01 = bf16_rne(p[2]) | (bf16_rne(p[3]) << 16);
                    unsigned pk10 = bf16_rne(p[4]) | (bf16_rne(p[5]) << 16);
                    unsigned pk11 = bf16_rne(p[6]) | (bf16_rne(p[7]) << 16);
                    int srcA = ((lane & 16) << 1) | lq;
                    int srcB = srcA + 16;
                    unsigned a00 = (unsigned)__shfl((int)pk00, srcA);
                    unsigned a01 = (unsigned)__shfl((int)pk01, srcA);
                    unsigned a10 = (unsigned)__shfl((int)pk10, srcA);
                    unsigned a11 = (unsigned)__shfl((int)pk11, srcA);
                    unsigned b00 = (unsigned)__shfl((int)pk00, srcB);
                    unsigned b01 = (unsigned)__shfl((int)pk01, srcB);
                    unsigned b10 = (unsigned)__shfl((int)pk10, srcB);
                    unsigned b11 = (unsigned)__shfl((int)pk11, srcB);
                    bool sel = (g >> 1) != 0;
                    union { unsigned u[4]; short8 v; } pf;
                    pf.u[0] = sel ? a10 : a00;
                    pf.u[1] = sel ? a11 : a01;
                    pf.u[2] = sel ? b10 : b00;
                    pf.u[3] = sel ? b11 : b01;

                    __builtin_amdgcn_s_setprio(1);
#pragma unroll
                    for (int dt = 0; dt < 16; ++dt) {
                        int d = dt * 16 + lq;
                        short8 vf = *(const short8*)&vtA[d * 32 + pvcc];
                        o[dt] = __builtin_amdgcn_mfma_f32_16x16x32_bf16(vf, pf.v, o[dt], 0, 0, 0);
                    }
                    __builtin_amdgcn_s_setprio(0);

                    if (kt + 1 < nkt) {
                        if (kt + 2 < nkt) {
                            asm volatile("s_waitcnt vmcnt(6)" ::: "memory");
                        } else {
                            asm volatile("s_waitcnt vmcnt(0)" ::: "memory");
                        }
                        __builtin_amdgcn_s_barrier();
                        __builtin_amdgcn_sched_barrier(0);
                    }
                    u16* tp;
                    tp = khA; khA = khB; khB = khC; khC = tp;
                    tp = klA; klA = klB; klB = klC; klC = tp;
                    tp = vtA; vtA = vtB; vtB = vtC; vtC = tp;
                }
            }

            // exact masked-key lump: all masked logits == MASK_FILL
            float wl = __expf(MASK_FILL - m);      // m >= MASK_FILL always
            z += (float)(LL - cnt_k) * wl;
#pragma unroll
            for (int dt = 0; dt < 16; ++dt) {
                f32x4 vv = *(const f32x4*)(vsp + dt * 16 + 4 * g);
                o[dt] += wl * vv;
            }

            if (qvalid) {
                int qrow = qidx[b * LL + qslot];
                float zinv = 1.0f / z;
                float* orow = ob + ((size_t)b * LL + qrow) * DD + 4 * g;
#pragma unroll
                for (int dt = 0; dt < 16; ++dt) {
                    f32x4 vv = o[dt] * zinv;
                    *(f32x4*)(orow + dt * 16) = vv;
                }
            }
        }
    }
#undef STAGE
}

extern "C" void kernel_launch(void* const* d_in, const int* in_sizes, int n_in,
                              void* d_out, int out_size, void* d_ws, size_t ws_size,
                              hipStream_t stream)
{
    const float* v1      = (const float*)d_in[0];
    const void*  v1_mask = d_in[1];
    const float* v2      = (const float*)d_in[2];
    const void*  v2_mask = d_in[3];
    float* out = (float*)d_out;

    u16* v1h = (u16*)d_ws;           // compacted hi (row = compact slot)
    u16* v1l = v1h + ELEMS;
    u16* v2h = v1l + ELEMS;
    u16* v2l = v2h + ELEMS;
    u16* v1t = v2l + ELEMS;          // compacted transpose [b][d][slot]
    u16* v2t = v1t + ELEMS;
    int* qidx1 = (int*)(v2t + ELEMS);
    int* qcnt1 = qidx1 + NB * LL;
    int* qidx2 = qcnt1 + NB;
    int* qcnt2 = qidx2 + NB * LL;
    int* cm1   = qcnt2 + NB;
    int* cm2   = cm1 + NB * LL;
    int* pa1   = cm2 + NB * LL;      // posAll (exclusive prefix of unmasked)
    int* pa2   = pa1 + NB * LL;
    int* mflag = pa2 + NB * LL;
    float* part = (float*)(mflag + 16);          // [2][NB][16][256]
    float* vsum = part + 2 * NB * 16 * 256;      // [2][NB][256]
    int* ctr    = (int*)(vsum + 2 * NB * 256);   // [8] steal counters

    hipMemsetAsync(ctr, 0, 8 * sizeof(int), stream);

    mask_detect<<<dim3(1), dim3(256), 0, stream>>>(
        (const unsigned*)v1_mask, (const unsigned*)v2_mask, mflag);
    mask_convert<<<dim3(NB * LL / 256), dim3(256), 0, stream>>>(v1_mask, mflag, cm1);
    mask_convert<<<dim3(NB * LL / 256), dim3(256), 0, stream>>>(v2_mask, mflag, cm2);

    zero_rows<<<dim3(2 * NB * LL / 8), dim3(256), 0, stream>>>(cm1, cm2, out);
    build_qidx<<<dim3(NB), dim3(256), 0, stream>>>(cm1, qidx1, pa1, qcnt1);
    build_qidx<<<dim3(NB), dim3(256), 0, stream>>>(cm2, qidx2, pa2, qcnt2);

    prep2_kernel<<<dim3(2 * NB * 64), dim3(256), 0, stream>>>(
        v1, v1h, v1l, v1t, cm1, pa1, qidx1, qcnt1,
        v2, v2h, v2l, v2t, cm2, pa2, qidx2, qcnt2, part);
    vsum_reduce<<<dim3(2 * NB), dim3(256), 0, stream>>>(part, vsum);

    // persistent, work-stealing fused flash (1 block per CU)
    flash_fused<<<dim3(256), dim3(512), 0, stream>>>(
        v1h, v1l, v2h, v2l, v1t, v2t,
        qidx1, qcnt1, qidx2, qcnt2, vsum, ctr, out);
}